// Round 1
// 288.758 us; speedup vs baseline: 1.1418x; 1.1418x over previous
//
#include <hip/hip_runtime.h>

// Newton-Schulz matrix sqrt, 1024 batches of 128x128 SPD, 5 iterations.
// R5 (barrier-stall attack; numerics identical to R4):
//   - Tq panel DOUBLE-BUFFERED -> one barrier per phase (was two).
//     Staging into buf[t&1] overlaps phase t-1 MFMA; overwrite safety comes
//     from the compiler's lgkmcnt(0) drain at barrier(t-1) (last readers of
//     buf[t&1] were phase t-2).
//   - Unpadded XOR-swizzled LDS layouts to fit the extra panel in 160 KiB:
//       Y/Z: stride 128, 16B-unit swizzle unit^=(R&7)  (was S=136 padded)
//       Tq : stride 32,  16B-unit swizzle unit^=(C&3)  (was SQ=40 padded)
//     All six access patterns verified bank-minimal by hand.
//   - red[] aliases Tq buf1 (first staged at t=1, after barrier(0); all
//     waves read red before barrier(0)).
//   - s_setprio(1) around the phase MFMA cluster (stager/compute role-split
//     now exists -> T5 applicable).
// Model from R3/R4 counters: MfmaUtil 23%, VALUBusy 20%, HBM 6% -> stall-
// bound; staging serialization + 9 barriers/iter were the dominant stall.

#define NN 128

typedef short bf16x8  __attribute__((ext_vector_type(8)));
typedef short short4v __attribute__((ext_vector_type(4)));
typedef float f32x4   __attribute__((ext_vector_type(4)));

__device__ __forceinline__ float bf2f(short h) {
  union { unsigned u; float f; } c;
  c.u = ((unsigned)(unsigned short)h) << 16;
  return c.f;
}

__device__ __forceinline__ short f2bf_rne(float x) {
  union { float f; unsigned u; } c; c.f = x;
  unsigned u = c.u;
  return (short)((u + 0x7fffu + ((u >> 16) & 1u)) >> 16);
}

// hi = bit-truncated top 16 (error <= 2^-8|x|), lo = RNE(x - hi)
__device__ __forceinline__ void split_bf16(float x, short& h, short& l) {
  union { float f; unsigned u; } c; c.f = x;
  h = (short)(c.u >> 16);
  union { unsigned u; float f; } hf; hf.u = c.u & 0xFFFF0000u;
  l = f2bf_rne(x - hf.f);
}

__device__ __forceinline__ unsigned pack2(short a, short b) {
  return (unsigned)(unsigned short)a | ((unsigned)(unsigned short)b << 16);
}

// Swizzled LDS index helpers (index in shorts).
// Y/Z: [R][K], 128x128, unit = K>>3 (16B), unit ^= (R&7). All K accesses are
// 8-short (16B) or 4-short-at-K%8 in {0,4} (8B) -> never cross a unit.
__device__ __forceinline__ int yix(int R, int K) {
  return (R << 7) + ((((K >> 3) ^ R) & 7) << 3) + ((K >> 3) >= 8 ? 64 : 0) + (K & 7);
}
// NOTE: the branch above is wrong-looking; use the direct form instead:
__device__ __forceinline__ int yix2(int R, int K) {
  return (R << 7) + (((K >> 3) ^ (R & 7)) << 3) + (K & 7);
}
// Tq: [C][K], 128x32, unit = K>>3 (0..3), unit ^= (C&3).
__device__ __forceinline__ int tix(int C, int K) {
  return (C << 5) + (((K >> 3) ^ (C & 3)) << 3) + (K & 7);
}

#define YIX(R, K) yix2((R), (K))

#define MFMA3(ACC, AH, AL, BH, BL)                                        \
  ACC = __builtin_amdgcn_mfma_f32_16x16x32_bf16(AH, BH, ACC, 0, 0, 0);    \
  ACC = __builtin_amdgcn_mfma_f32_16x16x32_bf16(AH, BL, ACC, 0, 0, 0);    \
  ACC = __builtin_amdgcn_mfma_f32_16x16x32_bf16(AL, BH, ACC, 0, 0, 0);

__global__ __launch_bounds__(512, 1)
void ns_sqrt_kernel(const float* __restrict__ A, float* __restrict__ out) {
  __shared__ __align__(16) short Yhi[NN * NN];
  __shared__ __align__(16) short Ylo[NN * NN];
  __shared__ __align__(16) short Zhi[NN * NN];
  __shared__ __align__(16) short Zlo[NN * NN];
  __shared__ __align__(16) short Tq[2][2][NN * 32];  // [buf][hi=0/lo=1]

  // 163,840 B total == exactly the 160 KiB cap; red aliases Tq buf1.
  float* red = reinterpret_cast<float*>(&Tq[1][0][0]);

  const int tid  = threadIdx.x;
  const int wave = tid >> 6;
  const int lane = tid & 63;
  const int quad = lane >> 4;
  const int lrow = lane & 15;
  const int wr = wave >> 1, wc = wave & 1;
  const int RB = wr << 5, CB = wc << 6;   // 32x64 slab base

  #pragma unroll 1
  for (int sb = 0; sb < 2; ++sb) {
    const int b = (blockIdx.x << 1) + sb;
    const float* Ab = A + (size_t)b * (NN * NN);

    // ---- init: load all of A, Frobenius sum, store unnormalized split A ----
    float ss = 0.f;
    {
      const float4* p = reinterpret_cast<const float4*>(Ab);
      const int row = tid >> 2;          // 0..127
      const int c0  = (tid & 3) << 5;    // 0,32,64,96
      #pragma unroll
      for (int ch = 0; ch < 4; ++ch) {
        bf16x8 vh, vl;
        #pragma unroll
        for (int q = 0; q < 2; ++q) {
          float4 v = p[row * (NN / 4) + (c0 >> 2) + (ch << 1) + q];
          float xs[4] = {v.x, v.y, v.z, v.w};
          #pragma unroll
          for (int e = 0; e < 4; ++e) {
            float x = xs[e];
            ss += x * x;
            short hh, ll; split_bf16(x, hh, ll);
            vh[(q << 2) + e] = hh;
            vl[(q << 2) + e] = ll;
          }
        }
        const int o = YIX(row, c0 + (ch << 3));
        *(bf16x8*)&Yhi[o] = vh;
        *(bf16x8*)&Ylo[o] = vl;
      }
    }
    #pragma unroll
    for (int off = 32; off; off >>= 1) ss += __shfl_xor(ss, off, 64);
    if (lane == 0) red[wave] = ss;
    __syncthreads();
    float tot = 0.f;
    #pragma unroll
    for (int w = 0; w < 8; ++w) tot += red[w];
    const float normA = sqrtf(tot);
    const float rn    = 1.f / normA;
    const float s_out = sqrtf(normA);

    const f32x4 zero4 = {0.f, 0.f, 0.f, 0.f};

    #pragma unroll 1
    for (int it = 1; it <= 5; ++it) {
      const bool doQ = (it >= 2) && (it <= 4);   // it1: Z1 = T; it5: Z unused
      f32x4 accM[2][4];
      f32x4 accP[2][4];
      f32x4 accQ[2][4];
      #pragma unroll
      for (int i = 0; i < 2; ++i)
        #pragma unroll
        for (int j = 0; j < 4; ++j) { accP[i][j] = zero4; accQ[i][j] = zero4; }

      if (it == 1) {
        // M = A slab (symmetric b64 read); normalization folded via mscale
        #pragma unroll
        for (int i = 0; i < 2; ++i)
          #pragma unroll
          for (int j = 0; j < 4; ++j) {
            const int col  = CB + 16*j + lrow;
            const int row0 = RB + 16*i + (quad << 2);
            const int o = YIX(col, row0);
            short4v h = *(const short4v*)&Yhi[o];
            short4v l = *(const short4v*)&Ylo[o];
            #pragma unroll
            for (int r = 0; r < 4; ++r) accM[i][j][r] = bf2f(h[r]) + bf2f(l[r]);
          }
      } else {
        // M = Z*Y  (A = Z rows; B = Y rows via symmetry)
        #pragma unroll
        for (int i = 0; i < 2; ++i)
          #pragma unroll
          for (int j = 0; j < 4; ++j) accM[i][j] = zero4;
        #pragma unroll
        for (int kc = 0; kc < 4; ++kc) {
          const int k0 = (kc << 5) + (quad << 3);
          bf16x8 ah[2], al[2], bh[4], bl[4];
          #pragma unroll
          for (int i = 0; i < 2; ++i) {
            const int o = YIX(RB + lrow + 16*i, k0);
            ah[i] = *(const bf16x8*)&Zhi[o];
            al[i] = *(const bf16x8*)&Zlo[o];
          }
          #pragma unroll
          for (int j = 0; j < 4; ++j) {
            const int o = YIX(CB + lrow + 16*j, k0);
            bh[j] = *(const bf16x8*)&Yhi[o];
            bl[j] = *(const bf16x8*)&Ylo[o];
          }
          #pragma unroll
          for (int i = 0; i < 2; ++i)
            #pragma unroll
            for (int j = 0; j < 4; ++j) { MFMA3(accM[i][j], ah[i], al[i], bh[j], bl[j]); }
        }
      }

      // T = 1.5 I - 0.5*mscale*M, split immediately into packed regs
      const float mscale = (it == 1) ? rn : 1.0f;
      unsigned tp[2][4][2], tl[2][4][2];
      #pragma unroll
      for (int i = 0; i < 2; ++i)
        #pragma unroll
        for (int j = 0; j < 4; ++j) {
          short h[4], l[4];
          #pragma unroll
          for (int r = 0; r < 4; ++r) {
            float tv = -0.5f * mscale * accM[i][j][r];
            if (RB + 16*i + (quad << 2) + r == CB + 16*j + lrow) tv += 1.5f;
            split_bf16(tv, h[r], l[r]);
          }
          tp[i][j][0] = pack2(h[0], h[1]); tp[i][j][1] = pack2(h[2], h[3]);
          tl[i][j][0] = pack2(l[0], l[1]); tl[i][j][1] = pack2(l[2], l[3]);
        }

      // 4 phases over 32-row blocks of T, double-buffered panels.
      // Phase t: wave wr==t stages buf[t&1] (prev readers drained at
      // barrier t-1), ONE publish barrier, everyone computes.
      #pragma unroll 1
      for (int t = 0; t < 4; ++t) {
        short* __restrict__ th = &Tq[t & 1][0][0];
        short* __restrict__ tg = &Tq[t & 1][1][0];

        if (wr == t) {
          #pragma unroll
          for (int i = 0; i < 2; ++i) {
            const int kp0 = (i << 4) + (quad << 2);
            #pragma unroll
            for (int j = 0; j < 4; ++j) {
              const int col = CB + 16*j + lrow;
              const int o = tix(col, kp0);
              *(uint2*)&th[o] = make_uint2(tp[i][j][0], tp[i][j][1]);
              *(uint2*)&tg[o] = make_uint2(tl[i][j][0], tl[i][j][1]);
            }
          }
        }

        // A-fragments depend only on Y/Z (stable all phase-loop long):
        // issued above the barrier so their latency hides under the wait.
        const int k0 = (t << 5) + (quad << 3);
        bf16x8 ahY[2], alY[2], ahZ[2], alZ[2];
        #pragma unroll
        for (int i = 0; i < 2; ++i) {
          const int o = YIX(RB + lrow + 16*i, k0);
          ahY[i] = *(const bf16x8*)&Yhi[o];
          alY[i] = *(const bf16x8*)&Ylo[o];
        }
        if (doQ) {
          #pragma unroll
          for (int i = 0; i < 2; ++i) {
            const int o = YIX(RB + lrow + 16*i, k0);
            ahZ[i] = *(const bf16x8*)&Zhi[o];
            alZ[i] = *(const bf16x8*)&Zlo[o];
          }
        }

        __syncthreads();                   // publish Tq[t&1]

        const int kq = quad << 3;
        bf16x8 bh[4], bl[4];
        #pragma unroll
        for (int j = 0; j < 4; ++j) {
          const int o = tix(CB + 16*j + lrow, kq);
          bh[j] = *(const bf16x8*)&th[o];
          bl[j] = *(const bf16x8*)&tg[o];
        }
        __builtin_amdgcn_s_setprio(1);
        #pragma unroll
        for (int i = 0; i < 2; ++i)
          #pragma unroll
          for (int j = 0; j < 4; ++j) { MFMA3(accP[i][j], ahY[i], alY[i], bh[j], bl[j]); }
        if (doQ) {
          #pragma unroll
          for (int i = 0; i < 2; ++i)
            #pragma unroll
            for (int j = 0; j < 4; ++j) { MFMA3(accQ[i][j], ahZ[i], alZ[i], bh[j], bl[j]); }
        }
        __builtin_amdgcn_s_setprio(0);
      }
      __syncthreads();   // all reads of Y/Z/Tq complete

      if (it < 5) {
        // write-back (packed b64 "transposed" store = same matrix by symmetry)
        const float yscale = (it == 1) ? rn : 1.0f;
        #pragma unroll
        for (int i = 0; i < 2; ++i)
          #pragma unroll
          for (int j = 0; j < 4; ++j) {
            const int col  = CB + 16*j + lrow;
            const int row0 = RB + 16*i + (quad << 2);
            const int o = YIX(col, row0);
            short h[4], l[4];
            #pragma unroll
            for (int r = 0; r < 4; ++r) split_bf16(yscale * accP[i][j][r], h[r], l[r]);
            *(uint2*)&Yhi[o] = make_uint2(pack2(h[0], h[1]), pack2(h[2], h[3]));
            *(uint2*)&Ylo[o] = make_uint2(pack2(l[0], l[1]), pack2(l[2], l[3]));
            if (it == 1) {
              // Z1 = T: reuse the packed split regs directly
              *(uint2*)&Zhi[o] = make_uint2(tp[i][j][0], tp[i][j][1]);
              *(uint2*)&Zlo[o] = make_uint2(tl[i][j][0], tl[i][j][1]);
            } else {
              #pragma unroll
              for (int r = 0; r < 4; ++r) split_bf16(accQ[i][j][r], h[r], l[r]);
              *(uint2*)&Zhi[o] = make_uint2(pack2(h[0], h[1]), pack2(h[2], h[3]));
              *(uint2*)&Zlo[o] = make_uint2(pack2(l[0], l[1]), pack2(l[2], l[3]));
            }
          }
        __syncthreads();
      } else {
        // final: out = Y5 * sqrt(normA)  (fire-and-forget; overlaps next init)
        float* ob = out + (size_t)b * (NN * NN);
        #pragma unroll
        for (int i = 0; i < 2; ++i)
          #pragma unroll
          for (int j = 0; j < 4; ++j) {
            const int col  = CB + 16*j + lrow;
            const int row0 = RB + 16*i + (quad << 2);
            #pragma unroll
            for (int r = 0; r < 4; ++r)
              ob[(size_t)(row0 + r) * NN + col] = accP[i][j][r] * s_out;
          }
      }
    }
  }
}

extern "C" void kernel_launch(void* const* d_in, const int* in_sizes, int n_in,
                              void* d_out, int out_size, void* d_ws, size_t ws_size,
                              hipStream_t stream) {
  const float* A = (const float*)d_in[0];
  float* out = (float*)d_out;
  ns_sqrt_kernel<<<dim3(512), dim3(512), 0, stream>>>(A, out);
}